// Round 6
// baseline (633.054 us; speedup 1.0000x reference)
//
#include <hip/hip_runtime.h>
#include <hip/hip_bf16.h>
#include <stdint.h>
#include <math.h>

#define DEV __device__ __forceinline__

using bf16 = __hip_bfloat16;
typedef __attribute__((ext_vector_type(8))) short bf16x8;
typedef __attribute__((ext_vector_type(4))) float f32x4;

static constexpr int NB  = 8;
static constexpr int NSW = 512;
static constexpr int NSE = 128;
static constexpr int ND  = 1024;
static constexpr int NH  = 16;
static constexpr int NFF = 4096;
static constexpr int NS  = NSW + NSE;   // 640
static constexpr int NHD = 64;

DEV f32x4 mfma16(bf16x8 a, bf16x8 b, f32x4 c){
  return __builtin_amdgcn_mfma_f32_16x16x32_bf16(a, b, c, 0, 0, 0);
}

DEV void gload16(const bf16* g, bf16* l){
  __builtin_amdgcn_global_load_lds((const __attribute__((address_space(1))) void*)g,
                                   (__attribute__((address_space(3))) void*)l,
                                   16, 0, 0);
}

DEV bf16 tobf(float f){ return __float2bfloat16(f); }

union PK4 { bf16 h[4]; short4 s; };

// ---------- casts: fp32 -> bf16 concatenated hidden (B,NS,D) ----------
__global__ __launch_bounds__(256) void cast_word_k(const float* __restrict__ wh,
                                                   bf16* __restrict__ hid){
  long i = ((long)blockIdx.x*256 + threadIdx.x)*4;
  float4 v = *reinterpret_cast<const float4*>(wh + i);
  PK4 p; p.h[0]=tobf(v.x); p.h[1]=tobf(v.y); p.h[2]=tobf(v.z); p.h[3]=tobf(v.w);
  long row = i >> 10; int c = (int)(i & 1023);
  int b = (int)(row >> 9), s = (int)(row & 511);
  *reinterpret_cast<short4*>(hid + ((long)(b*NS + s) << 10) + c) = p.s;
}

__global__ __launch_bounds__(256) void cast_ent_k(const float* __restrict__ eh,
                                                  bf16* __restrict__ hid){
  long i = ((long)blockIdx.x*256 + threadIdx.x)*4;
  float4 v = *reinterpret_cast<const float4*>(eh + i);
  PK4 p; p.h[0]=tobf(v.x); p.h[1]=tobf(v.y); p.h[2]=tobf(v.z); p.h[3]=tobf(v.w);
  long row = i >> 10; int c = (int)(i & 1023);
  int b = (int)(row >> 7), s = (int)(row & 127);
  *reinterpret_cast<short4*>(hid + ((long)(b*NS + NSW + s) << 10) + c) = p.s;
}

// ---------- batched 1024x1024 weight transpose+cast ----------
struct TP7 { const float* src[7]; bf16* dst[7]; };

__global__ void transpose7_k(TP7 tp){
  __shared__ float tile[32][33];
  const float* in = tp.src[blockIdx.z];
  bf16* out = tp.dst[blockIdx.z];
  const int c0 = blockIdx.x*32, r0 = blockIdx.y*32;
  const int tx = threadIdx.x, ty = threadIdx.y;
  #pragma unroll
  for (int i=0;i<4;i++)
    tile[ty + i*8][tx] = in[(long)(r0 + ty + i*8)*1024 + c0 + tx];
  __syncthreads();
  #pragma unroll
  for (int i=0;i<4;i++){
    int rr = ty + i*8;
    out[(long)(c0 + rr)*1024 + r0 + tx] = tobf(tile[tx][rr]);
  }
}

__global__ void transpose_cast_k(const float* __restrict__ in, bf16* __restrict__ out,
                                 int R, int C){
  __shared__ float tile[32][33];
  const int c0 = blockIdx.x*32, r0 = blockIdx.y*32;
  const int tx = threadIdx.x, ty = threadIdx.y;
  #pragma unroll
  for (int i=0;i<4;i++)
    tile[ty + i*8][tx] = in[(long)(r0 + ty + i*8)*C + c0 + tx];
  __syncthreads();
  #pragma unroll
  for (int i=0;i<4;i++){
    int rr = ty + i*8;
    out[(long)(c0 + rr)*R + r0 + tx] = tobf(tile[tx][rr]);
  }
}

__global__ void bias_concat_k(const float* __restrict__ bq, const float* __restrict__ bw2e,
                              const float* __restrict__ be2w, const float* __restrict__ be2e,
                              const float* __restrict__ bk, const float* __restrict__ bv,
                              float* __restrict__ bQw, float* __restrict__ bQe,
                              float* __restrict__ bKV){
  int i = blockIdx.x*256 + threadIdx.x;
  bQw[i] = bq[i];   bQw[1024+i] = bw2e[i];
  bQe[i] = be2w[i]; bQe[1024+i] = be2e[i];
  bKV[i] = bk[i];   bKV[1024+i] = bv[i];
}

// =====================================================================
// 256-wide deep-pipelined GEMM core. BM=256, BK=64, 512 threads (8 waves,
// 2Mx4N). NF = n-frags/wave (4 -> BN=256, 2 -> BN=128).
// LDS: fragment-linear layout (zero bank conflicts).
// Pipeline: 2 K-tile buffers, 4 half-stages/tile, counted vmcnt gates.
// vmcnt ledger (NF=4, loads/half-stage A=2,B=2): prologue 8 outstanding;
// every steady gate sees 8, vmcnt(4) retires exactly the half consumed.
// FINAL gate (t=NT-1,ks=1) sees only 4 outstanding -> must drain with
// vmcnt(0) (R5 bug: vmcnt(4) was a no-op there -> raced the last K-half).
// =====================================================================
template<int NF>
DEV void stA(bf16* reg, const bf16* a0, const bf16* a1, int koff, int tid){
  gload16(a0 + koff, reg + tid*8);
  gload16(a1 + koff, reg + (512 + tid)*8);
}
template<int NF>
DEV void stB(bf16* reg, const bf16* b0, const bf16* b1, int koff, int tid){
  gload16(b0 + koff, reg + tid*8);
  if constexpr (NF == 4) gload16(b1 + koff, reg + (512 + tid)*8);
}

template<int NF>
DEV void g256_core(const bf16* a0, const bf16* a1,
                   const bf16* b0, const bf16* b1,
                   int NT, bf16* lds, f32x4 (&acc)[8][NF],
                   int tid, int wr, int wc, int lane){
  constexpr int AKH  = 8192;        // elems per A half (256x32)
  constexpr int BKH  = NF*2048;     // elems per B half (BN x 32)
  constexpr int BUFE = 2*AKH + 2*BKH;
  auto Areg = [&](int buf,int kh){ return lds + buf*BUFE + kh*AKH; };
  auto Breg = [&](int buf,int kh){ return lds + buf*BUFE + 2*AKH + kh*BKH; };
  auto gate = [&](bool last){
    if (last){
      asm volatile("s_waitcnt vmcnt(0)" ::: "memory");
    } else if constexpr (NF == 4){
      asm volatile("s_waitcnt vmcnt(4)" ::: "memory");
    } else {
      asm volatile("s_waitcnt vmcnt(3)" ::: "memory");
    }
    __builtin_amdgcn_sched_barrier(0);
    asm volatile("s_barrier" ::: "memory");
    __builtin_amdgcn_sched_barrier(0);
  };
  // prologue: tile 0 -> buf0, in gate-consistent order
  stA<NF>(Areg(0,0), a0, a1, 0,  tid);
  stB<NF>(Breg(0,0), b0, b1, 0,  tid);
  stA<NF>(Areg(0,1), a0, a1, 32, tid);
  stB<NF>(Breg(0,1), b0, b1, 32, tid);
  int kt = 0;
  for (int t=0; t<NT; ++t){
    const int c = t & 1;
    const bool more = (t+1 < NT);
    const int kn = kt + 64;
    #pragma unroll
    for (int ks=0; ks<2; ++ks){
      gate(!more && ks==1);                    // retires buf c kh=ks data
      if (more) stA<NF>(Areg(c^1, ks), a0, a1, kn + ks*32, tid);
      const bf16* Ar = Areg(c, ks);
      const bf16* Br = Breg(c, ks);
      bf16x8 bfr[NF], afr[4];
      #pragma unroll
      for (int nf=0; nf<NF; ++nf)
        bfr[nf] = *reinterpret_cast<const bf16x8*>(Br + (((wc*NF+nf)<<6) + lane)*8);
      #pragma unroll
      for (int m=0; m<4; ++m)
        afr[m] = *reinterpret_cast<const bf16x8*>(Ar + (((wr*8+m)<<6) + lane)*8);
      __builtin_amdgcn_s_setprio(1);
      #pragma unroll
      for (int m=0; m<4; ++m)
        #pragma unroll
        for (int nf=0; nf<NF; ++nf)
          acc[m][nf] = mfma16(afr[m], bfr[nf], acc[m][nf]);
      __builtin_amdgcn_s_setprio(0);
      if (more) stB<NF>(Breg(c^1, ks), b0, b1, kn + ks*32, tid);
      #pragma unroll
      for (int m=0; m<4; ++m)
        afr[m] = *reinterpret_cast<const bf16x8*>(Ar + (((wr*8+4+m)<<6) + lane)*8);
      __builtin_amdgcn_s_setprio(1);
      #pragma unroll
      for (int m=0; m<4; ++m)
        #pragma unroll
        for (int nf=0; nf<NF; ++nf)
          acc[4+m][nf] = mfma16(afr[m], bfr[nf], acc[4+m][nf]);
      __builtin_amdgcn_s_setprio(0);
    }
    kt = kn;
  }
}

// ---------- fused projections: [Q (word|ent) | KV] in one dispatch ----------
__global__ __launch_bounds__(512, 2) void proj_k(const bf16* __restrict__ hid,
    const bf16* __restrict__ WqwT, const bf16* __restrict__ WqeT,
    const bf16* __restrict__ WkvT,
    const float* __restrict__ bQw, const float* __restrict__ bQe,
    const float* __restrict__ bKV,
    bf16* __restrict__ Qwb, bf16* __restrict__ Qeb,
    bf16* __restrict__ KVb, bf16* __restrict__ Vt){
  __shared__ __align__(16) bf16 lds[2*(2*8192 + 2*8192)];   // 128 KB
  const int tid = threadIdx.x, wid = tid>>6, lane = tid&63;
  const int wr = wid>>2, wc = wid&3, lr = lane&15, lg = lane>>4;
  int wg = blockIdx.x;
  { int xcd = wg & 7, idx = wg >> 3; wg = xcd*40 + idx; }   // bijective, 320=8*40
  const bool isKV = (wg >= 160);
  const int loc = isKV ? wg - 160 : wg;
  const int m0 = (loc >> 3)*256, n0 = (loc & 7)*256;
  const bool word = (m0 < 4096);

  const int la = lane & 15, ksub = (lane>>4)*8;
  auto hidrow = [&](int r)->long{
    if (isKV) return r;
    if (word) return (long)((r>>9)*640 + (r&511));
    int r2 = r - 4096; return (long)((r2>>7)*640 + 512 + (r2&127));
  };
  const bf16* a0 = hid + hidrow(m0 + wid*16 + la)*1024 + ksub;
  const bf16* a1 = hid + hidrow(m0 + (wid+8)*16 + la)*1024 + ksub;
  const bf16* Bt = isKV ? WkvT : (word ? WqwT : WqeT);
  const bf16* b0 = Bt + (long)(n0 + wid*16 + la)*1024 + ksub;
  const bf16* b1 = Bt + (long)(n0 + (wid+8)*16 + la)*1024 + ksub;

  f32x4 acc[8][4];
  #pragma unroll
  for (int m=0;m<8;m++)
    #pragma unroll
    for (int n=0;n<4;n++) acc[m][n] = (f32x4){0.f,0.f,0.f,0.f};

  g256_core<4>(a0, a1, b0, b1, 16, lds, acc, tid, wr, wc, lane);

  const float* bias = isKV ? bKV : (word ? bQw : bQe);
  #pragma unroll
  for (int m=0;m<8;m++){
    const int rbase = m0 + wr*128 + m*16 + lg*4;
    #pragma unroll
    for (int nf=0;nf<4;nf++){
      const int col = n0 + wc*64 + nf*16 + lr;
      const float bsv = bias[col];
      #pragma unroll
      for (int r=0;r<4;r++){
        const int rw = rbase + r;
        const float v = acc[m][nf][r] + bsv;
        if (!isKV){
          if (word) Qwb[(long)rw*2048 + col] = tobf(v);
          else      Qeb[(long)(rw-4096)*2048 + col] = tobf(v);
        } else {
          if (col < 1024){
            KVb[(long)rw*2048 + col] = tobf(v);
          } else {
            int b = rw / NS, s = rw % NS, hh = (col-1024)>>6, dd = (col-1024)&63;
            Vt[((long)((b*NH + hh)*NHD + dd))*NS + s] = tobf(v);
          }
        }
      }
    }
  }
}

// ---------- FFN1: GELU(attnB @ WiT^T + bi) -> inter, 256x256 tiles ----------
__global__ __launch_bounds__(512, 2) void ffn1_k(const bf16* __restrict__ A,
    const bf16* __restrict__ Bt, const float* __restrict__ bias,
    bf16* __restrict__ out){
  __shared__ __align__(16) bf16 lds[2*(2*8192 + 2*8192)];   // 128 KB
  const int tid = threadIdx.x, wid = tid>>6, lane = tid&63;
  const int wr = wid>>2, wc = wid&3, lr = lane&15, lg = lane>>4;
  int wg = blockIdx.x;
  { int xcd = wg & 7, idx = wg >> 3; wg = xcd*40 + idx; }   // 320=8*40
  const int m0 = (wg >> 4)*256, n0 = (wg & 15)*256;         // 20 x 16

  const int la = lane & 15, ksub = (lane>>4)*8;
  const bf16* a0 = A + (long)(m0 + wid*16 + la)*1024 + ksub;
  const bf16* a1 = A + (long)(m0 + (wid+8)*16 + la)*1024 + ksub;
  const bf16* b0 = Bt + (long)(n0 + wid*16 + la)*1024 + ksub;
  const bf16* b1 = Bt + (long)(n0 + (wid+8)*16 + la)*1024 + ksub;

  f32x4 acc[8][4];
  #pragma unroll
  for (int m=0;m<8;m++)
    #pragma unroll
    for (int n=0;n<4;n++) acc[m][n] = (f32x4){0.f,0.f,0.f,0.f};

  g256_core<4>(a0, a1, b0, b1, 16, lds, acc, tid, wr, wc, lane);

  #pragma unroll
  for (int m=0;m<8;m++){
    const int rbase = m0 + wr*128 + m*16 + lg*4;
    #pragma unroll
    for (int nf=0;nf<4;nf++){
      const int col = n0 + wc*64 + nf*16 + lr;
      const float bsv = bias[col];
      #pragma unroll
      for (int r=0;r<4;r++){
        float v = acc[m][nf][r] + bsv;
        float ge = 0.5f*v*(1.0f + erff(v*0.70710678118654752f));
        out[(long)(rbase+r)*NFF + col] = tobf(ge);
      }
    }
  }
}

// ---------- 256x128-tile split-K=2 fp32-out GEMM (Wo and FFN2) ----------
__global__ __launch_bounds__(512, 2) void ws_k(const bf16* __restrict__ A, int lda,
    const bf16* __restrict__ Bt, const float* __restrict__ bias,
    float* __restrict__ out0, float* __restrict__ out1, int Kc){
  __shared__ __align__(16) bf16 lds[2*(2*8192 + 2*4096)];   // 96 KB
  const int tid = threadIdx.x, wid = tid>>6, lane = tid&63;
  const int wr = wid>>2, wc = wid&3, lr = lane&15, lg = lane>>4;
  int wg = blockIdx.x;
  { int xcd = wg & 7, idx = wg >> 3; wg = xcd*20 + idx; }   // 160=8*20
  const int m0 = (wg >> 3)*256, n0 = (wg & 7)*128;          // 20 x 8
  const int kt0 = blockIdx.z * Kc;

  const int la = lane & 15, ksub = (lane>>4)*8;
  const bf16* a0 = A + (long)(m0 + wid*16 + la)*lda + kt0 + ksub;
  const bf16* a1 = A + (long)(m0 + (wid+8)*16 + la)*lda + kt0 + ksub;
  const bf16* b0 = Bt + (long)(n0 + wid*16 + la)*lda + kt0 + ksub;

  f32x4 acc[8][2];
  #pragma unroll
  for (int m=0;m<8;m++)
    #pragma unroll
    for (int n=0;n<2;n++) acc[m][n] = (f32x4){0.f,0.f,0.f,0.f};

  g256_core<2>(a0, a1, b0, b0, Kc/64, lds, acc, tid, wr, wc, lane);

  float* out = blockIdx.z ? out1 : out0;
  #pragma unroll
  for (int m=0;m<8;m++){
    const int rbase = m0 + wr*128 + m*16 + lg*4;
    #pragma unroll
    for (int nf=0;nf<2;nf++){
      const int col = n0 + wc*32 + nf*16 + lr;
      const float bsv = blockIdx.z ? 0.f : bias[col];
      #pragma unroll
      for (int r=0;r<4;r++)
        out[(long)(rbase+r)*1024 + col] = acc[m][nf][r] + bsv;
    }
  }
}

// ---------- fused entity-aware flash attention, split-K x4 (unchanged) ----------
__global__ __launch_bounds__(256) void attn_k(
    const bf16* __restrict__ Qw, const bf16* __restrict__ Qe,
    const bf16* __restrict__ KV, const bf16* __restrict__ Vt,
    const float* __restrict__ wm, const float* __restrict__ em,
    bf16* __restrict__ ctx){
  __shared__ __align__(16) bf16 Plds[4][2][16*40];
  __shared__ float mred[4][2][16];
  __shared__ float lred[4][2][16];
  __shared__ __align__(16) float accred[4][16][64];
  const int tid = threadIdx.x, wid = tid>>6, lane = tid&63;
  const int lr = lane&15, lg = lane>>4;
  const int w   = blockIdx.x;
  const int b   = w / (NH*20);
  const int rem = w % (NH*20);
  const int h   = rem / 20;
  const int q0  = (rem % 20)*32;

  const bf16* Qbase; long qrow0;
  if (q0 < NSW){ Qbase = Qw; qrow0 = (long)b*NSW + q0; }
  else         { Qbase = Qe; qrow0 = (long)b*NSE + (q0 - NSW); }

  bf16x8 qA[2][2], qB[2][2];
  #pragma unroll
  for (int m=0;m<2;m++)
    #pragma unroll
    for (int dc=0; dc<2; dc++){
      long o = (qrow0 + m*16 + lr)*2048 + h*NHD + dc*32 + lg*8;
      qA[m][dc] = *reinterpret_cast<const bf16x8*>(Qbase + o);
      qB[m][dc] = *reinterpret_cast<const bf16x8*>(Qbase + o + 1024);
    }

  const f32x4 zero = {0.f,0.f,0.f,0.f};
  f32x4 cacc[2][4];
  float mrow[2][4], lsum[2][4];
  #pragma unroll
  for (int m=0;m<2;m++){
    #pragma unroll
    for (int dt=0;dt<4;dt++) cacc[m][dt] = zero;
    #pragma unroll
    for (int r=0;r<4;r++){ mrow[m][r] = -1e30f; lsum[m][r] = 0.f; }
  }

  const bf16* Kbase = KV + (long)b*NS*2048 + h*NHD;
  const bf16* Vbase = Vt + (long)((b*NH + h)*NHD)*NS;

  for (int kt=wid*5; kt<wid*5+5; kt++){
    const int k0 = kt*32;
    const bool word = (k0 < NSW);

    bf16x8 kf[2][2], vf[4];
    #pragma unroll
    for (int sub=0;sub<2;sub++)
      #pragma unroll
      for (int dc=0;dc<2;dc++)
        kf[sub][dc] = *reinterpret_cast<const bf16x8*>(
            Kbase + (long)(k0 + sub*16 + lr)*2048 + dc*32 + lg*8);
    #pragma unroll
    for (int dt=0;dt<4;dt++)
      vf[dt] = *reinterpret_cast<const bf16x8*>(
          Vbase + (long)(dt*16 + lr)*NS + k0 + lg*8);

    float msk0, msk1;
    { int k = k0 + lr;
      msk0 = word ? wm[b*NSW + k]      : em[b*NSE + (k - NSW)];
      msk1 = word ? wm[b*NSW + k + 16] : em[b*NSE + (k + 16 - NSW)];
    }

    f32x4 sc[2][2];
    #pragma unroll
    for (int m=0;m<2;m++){ sc[m][0]=zero; sc[m][1]=zero; }
    __builtin_amdgcn_s_setprio(1);
    #pragma unroll
    for (int m=0;m<2;m++)
      #pragma unroll
      for (int sub=0;sub<2;sub++)
        #pragma unroll
        for (int dc=0;dc<2;dc++){
          const bf16x8 q = word ? qA[m][dc] : qB[m][dc];
          sc[m][sub] = mfma16(q, kf[sub][dc], sc[m][sub]);
        }
    __builtin_amdgcn_s_setprio(0);

    #pragma unroll
    for (int m=0;m<2;m++){
      bf16* pw = &Plds[wid][m][0];
      #pragma unroll
      for (int r=0;r<4;r++){
        float s0 = sc[m][0][r]*0.125f + msk0;
        float s1 = sc[m][1][r]*0.125f + msk1;
        float t = fmaxf(s0, s1);
        #pragma unroll
        for (int o=8;o;o>>=1) t = fmaxf(t, __shfl_xor(t, o, 16));
        float mn = fmaxf(mrow[m][r], t);
        float al = __expf(mrow[m][r] - mn);
        mrow[m][r] = mn;
        float p0 = __expf(s0 - mn), p1 = __expf(s1 - mn);
        float ps = p0 + p1;
        #pragma unroll
        for (int o=8;o;o>>=1) ps += __shfl_xor(ps, o, 16);
        lsum[m][r] = lsum[m][r]*al + ps;
        pw[(lg*4+r)*40 + lr]      = tobf(p0);
        pw[(lg*4+r)*40 + 16 + lr] = tobf(p1);
        #pragma unroll
        for (int dt=0;dt<4;dt++) cacc[m][dt][r] *= al;
      }
    }

    __builtin_amdgcn_s_setprio(1);
    #pragma unroll
    for (int m=0;m<2;m++){
      bf16x8 pa = *reinterpret_cast<const bf16x8*>(&Plds[wid][m][0] + lr*40 + lg*8);
      #pragma unroll
      for (int dt=0;dt<4;dt++)
        cacc[m][dt] = mfma16(pa, vf[dt], cacc[m][dt]);
    }
    __builtin_amdgcn_s_setprio(0);
  }

  #pragma unroll
  for (int m=0;m<2;m++)
    #pragma unroll
    for (int r=0;r<4;r++)
      if (lr == 0){
        mred[wid][m][lg*4+r] = mrow[m][r];
        lred[wid][m][lg*4+r] = lsum[m][r];
      }
  __syncthreads();

  float Lg[2][4], scl[2][4];
  #pragma unroll
  for (int m=0;m<2;m++)
    #pragma unroll
    for (int r=0;r<4;r++){
      const int row = lg*4 + r;
      float M0 = fmaxf(fmaxf(mred[0][m][row], mred[1][m][row]),
                       fmaxf(mred[2][m][row], mred[3][m][row]));
      float lt = 0.f;
      #pragma unroll
      for (int ww=0; ww<4; ww++)
        lt += lred[ww][m][row] * __expf(mred[ww][m][row] - M0);
      Lg[m][r]  = lt;
      scl[m][r] = __expf(mrow[m][r] - M0);
    }

  const long crow = (long)b*NS + q0;
  #pragma unroll
  for (int m=0;m<2;m++){
    #pragma unroll
    for (int dt=0;dt<4;dt++)
      #pragma unroll
      for (int r=0;r<4;r++)
        accred[wid][dt*4+r][lane] = cacc[m][dt][r] * scl[m][r];
    __syncthreads();
    { const int dt = wid;
      #pragma unroll
      for (int r=0;r<4;r++){
        float s = accred[0][dt*4+r][lane] + accred[1][dt*4+r][lane]
                + accred[2][dt*4+r][lane] + accred[3][dt*4+r][lane];
        s /= Lg[m][r];
        ctx[(crow + m*16 + lg*4 + r)*ND + h*NHD + dt*16 + lr] = tobf(s);
      }
    }
    __syncthreads();
  }
}

// ---------- LayerNorm kernels (fp32, fused residual + split-K partial add) ----------
DEV void block_red2(float& s1, float& s2){
  __shared__ float red[8];
  #pragma unroll
  for (int o=32;o;o>>=1){ s1 += __shfl_down(s1,o); s2 += __shfl_down(s2,o); }
  int wid = threadIdx.x>>6, lane = threadIdx.x&63;
  if (lane==0){ red[wid]=s1; red[4+wid]=s2; }
  __syncthreads();
  s1 = red[0]+red[1]+red[2]+red[3];
  s2 = red[4]+red[5]+red[6]+red[7];
}

__global__ __launch_bounds__(256) void ln1_k(const float* __restrict__ ctxO,
    const float* __restrict__ ctxO1,
    const float* __restrict__ wh, const float* __restrict__ eh,
    const float* __restrict__ g, const float* __restrict__ be,
    float* __restrict__ outF, bf16* __restrict__ outB){
  const int row = blockIdx.x;
  const int b = row / NS, s = row % NS;
  const float* resid = (s < NSW) ? wh + ((long)(b*NSW + s))*ND
                                 : eh + ((long)(b*NSE + (s-NSW)))*ND;
  const int t = threadIdx.x;
  float4 xv = reinterpret_cast<const float4*>(ctxO + (long)row*ND)[t];
  float4 x1 = reinterpret_cast<const float4*>(ctxO1 + (long)row*ND)[t];
  float4 rv = reinterpret_cast<const float4*>(resid)[t];
  float4 x = make_float4(xv.x+x1.x+rv.x, xv.y+x1.y+rv.y, xv.z+x1.z+rv.z, xv.w+x1.w+rv.w);
  float s1 = x.x+x.y+x.z+x.w;
  float s2 = x.x*x.x + x.y*x.y + x.z*x.z + x.w*x.w;
  block_red2(s1, s2);
  float mean = s1 * (1.f/ND);
  float var  = s2 * (1.f/ND) - mean*mean;
  float rstd = rsqrtf(var + 1e-12f);
  float4 gv = reinterpret_cast<const float4*>(g)[t];
  float4 bv = reinterpret_cast<const float4*>(be)[t];
  float4 y = make_float4(gv.x*(x.x-mean)*rstd + bv.x,
                         gv.y*(x.y-mean)*rstd + bv.y,
                         gv.z*(x.z-mean)*rstd + bv.z,
                         gv.w*(x.w-mean)*rstd + bv.w);
  reinterpret_cast<float4*>(outF + (long)row*ND)[t] = y;
  PK4 p; p.h[0]=tobf(y.x); p.h[1]=tobf(y.y); p.h[2]=tobf(y.z); p.h[3]=tobf(y.w);
  reinterpret_cast<short4*>(outB + (long)row*ND)[t] = p.s;
}

__global__ __launch_bounds__(256) void ln2_k(const float* __restrict__ ffo,
    const float* __restrict__ ffo1,
    const float* __restrict__ attnF, const float* __restrict__ g,
    const float* __restrict__ be, float* __restrict__ out){
  const int row = blockIdx.x;
  const int b = row / NS, s = row % NS;
  const int t = threadIdx.x;
  float4 xv = reinterpret_cast<const float4*>(ffo + (long)row*ND)[t];
  float4 x1 = reinterpret_cast<const float4*>(ffo1 + (long)row*ND)[t];
  float4 rv = reinterpret_cast<const float4*>(attnF + (long)row*ND)[t];
  float4 x = make_float4(xv.x+x1.x+rv.x, xv.y+x1.y+rv.y, xv.z+x1.z+rv.z, xv.w+x1.w+rv.w);
  float s1 = x.x+x.y+x.z+x.w;
  float s2 = x.x*x.x + x.y*x.y + x.z*x.z + x.w*x.w;
  block_red2(s1, s2);
  float mean = s1 * (1.f/ND);
  float var  = s2 * (1.f/ND) - mean*mean;
  float rstd = rsqrtf(var + 1e-12f);
  float4 gv = reinterpret_cast<const float4*>(g)[t];
  float4 bv = reinterpret_cast<const float4*>(be)[t];
  float4 y = make_float4(gv.x*(x.x-mean)*rstd + bv.x,
                         gv.y*(x.y-mean)*rstd + bv.y,
                         gv.z*(x.z-mean)*rstd + bv.z,
                         gv.w*(x.w-mean)*rstd + bv.w);
  float* op = (s < NSW) ? out + ((long)(b*NSW+s))*ND
                        : out + (long)NB*NSW*ND + ((long)(b*NSE + (s-NSW)))*ND;
  reinterpret_cast<float4*>(op)[t] = y;
}

// ---------- host ----------
extern "C" void kernel_launch(void* const* d_in, const int* in_sizes, int n_in,
                              void* d_out, int out_size, void* d_ws, size_t ws_size,
                              hipStream_t stream){
  (void)in_sizes; (void)n_in; (void)out_size; (void)ws_size;
  const float* wh   = (const float*)d_in[0];
  const float* eh   = (const float*)d_in[1];
  const float* wm   = (const float*)d_in[2];
  const float* em   = (const float*)d_in[3];
  const float* Wq   = (const float*)d_in[4];   const float* bq   = (const float*)d_in[5];
  const float* Ww2e = (const float*)d_in[6];   const float* bw2e = (const float*)d_in[7];
  const float* We2w = (const float*)d_in[8];   const float* be2w = (const float*)d_in[9];
  const float* We2e = (const float*)d_in[10];  const float* be2e = (const float*)d_in[11];
  const float* Wk   = (const float*)d_in[12];  const float* bk   = (const float*)d_in[13];
  const float* Wv   = (const float*)d_in[14];  const float* bv   = (const float*)d_in[15];
  const float* Wo   = (const float*)d_in[16];  const float* bo   = (const float*)d_in[17];
  const float* g1   = (const float*)d_in[18];  const float* b1   = (const float*)d_in[19];
  const float* Wi   = (const float*)d_in[20];  const float* bi   = (const float*)d_in[21];
  const float* Wout = (const float*)d_in[22];  const float* bout = (const float*)d_in[23];
  const float* g2   = (const float*)d_in[24];  const float* b2   = (const float*)d_in[25];
  float* out = (float*)d_out;

  char* ws = (char*)d_ws;
  size_t off = 0;
  auto alloc = [&](size_t bytes)->char*{
    char* p = ws + off; off += (bytes + 255) & ~(size_t)255; return p;
  };

  bf16* hid   = (bf16*)alloc((size_t)NB*NS*ND*2);     // 10 MB
  bf16* WqwT  = (bf16*)alloc((size_t)2048*ND*2);      //  4 MB  [Wq^T ; Ww2e^T]
  bf16* WqeT  = (bf16*)alloc((size_t)2048*ND*2);      //  4 MB  [We2w^T ; We2e^T]
  bf16* WkvT  = (bf16*)alloc((size_t)2048*ND*2);      //  4 MB  [Wk^T ; Wv^T]
  float* part1 = (float*)hid;                          // 20 MB reuse after proj
  bf16* WoT   = (bf16*)alloc((size_t)ND*ND*2);
  bf16* WiT   = (bf16*)alloc((size_t)NFF*ND*2);
  bf16* WoutT = (bf16*)alloc((size_t)ND*NFF*2);
  float* bQw  = (float*)alloc(2048*4);
  float* bQe  = (float*)alloc(2048*4);
  float* bKV  = (float*)alloc(2048*4);

  // union region: {Qw, Qe, KV, Vt} reused as {inter, attnB} after attention
  char* u1 = alloc((size_t)52428800);
  bf16* Qwb = (bf16*)u1;                               // (B*SW, 2048) = 16 MB
  bf16* Qeb = Qwb + (size_t)NB*NSW*2048;               // (B*SE, 2048) = 4 MB
  bf16* KVb = Qeb + (size_t)NB*NSE*2048;               // (B*NS, 2048) = 20 MB
  bf16* Vt  = KVb + (size_t)NB*NS*2048;                // (B,H,64,NS) = 10 MB
  bf16* inter = (bf16*)u1;                             // (B*NS, 4096) = 40 MB
  bf16* attnB = (bf16*)(u1 + (size_t)41943040);        // (B*NS, 1024) = 10 MB (over Vt)

  bf16*  ctx   = (bf16*)alloc((size_t)NB*NS*ND*2);
  float* ctxO  = (float*)alloc((size_t)NB*NS*ND*4);    // reused as ffo
  float* ffo   = ctxO;
  float* attnF = (float*)alloc((size_t)NB*NS*ND*4);

  dim3 tb(32,8);
  cast_word_k<<<4096, 256, 0, stream>>>(wh, hid);
  cast_ent_k <<<1024, 256, 0, stream>>>(eh, hid);

  TP7 tp;
  tp.src[0]=Wq;   tp.dst[0]=WqwT;
  tp.src[1]=Ww2e; tp.dst[1]=WqwT + (size_t)1024*1024;
  tp.src[2]=We2w; tp.dst[2]=WqeT;
  tp.src[3]=We2e; tp.dst[3]=WqeT + (size_t)1024*1024;
  tp.src[4]=Wk;   tp.dst[4]=WkvT;
  tp.src[5]=Wv;   tp.dst[5]=WkvT + (size_t)1024*1024;
  tp.src[6]=Wo;   tp.dst[6]=WoT;
  transpose7_k<<<dim3(32,32,7), tb, 0, stream>>>(tp);
  transpose_cast_k<<<dim3(128,32), tb, 0, stream>>>(Wi,   WiT,   ND, NFF);
  transpose_cast_k<<<dim3(32,128), tb, 0, stream>>>(Wout, WoutT, NFF, ND);
  bias_concat_k<<<4, 256, 0, stream>>>(bq, bw2e, be2w, be2e, bk, bv, bQw, bQe, bKV);

  proj_k<<<320, 512, 0, stream>>>(hid, WqwT, WqeT, WkvT, bQw, bQe, bKV,
                                  Qwb, Qeb, KVb, Vt);

  attn_k<<<2560, 256, 0, stream>>>(Qwb, Qeb, KVb, Vt, wm, em, ctx);

  ws_k<<<dim3(160,1,2), 512, 0, stream>>>(ctx, 1024, WoT, bo, ctxO, part1, 512);
  ln1_k<<<5120, 256, 0, stream>>>(ctxO, part1, wh, eh, g1, b1, attnF, attnB);
  ffn1_k<<<320, 512, 0, stream>>>(attnB, WiT, bi, inter);
  ws_k<<<dim3(160,1,2), 512, 0, stream>>>(inter, 4096, WoutT, bout, ffo, part1, 2048);
  ln2_k<<<5120, 256, 0, stream>>>(ffo, part1, attnF, g2, b2, out);
}